// Round 3
// baseline (1142.184 us; speedup 1.0000x reference)
//
#include <hip/hip_runtime.h>

#define NPTS 524288
#define NSEG 64
#define RB 32                   // rows per block
#define NBLK (NPTS / RB)        // 16384 blocks
#define MAXP (NBLK + NSEG)      // max part records

typedef __bf16 bf16x8 __attribute__((ext_vector_type(8)));
typedef float f32x4 __attribute__((ext_vector_type(4)));

__device__ __forceinline__ unsigned int f2bf(float f) {
  unsigned int u = __float_as_uint(f);
  return (u + 0x7FFFu + ((u >> 16) & 1u)) >> 16;  // RNE bf16
}

// Branchless erf, Abramowitz-Stegun 7.1.26, |err| <= 1.5e-7
__device__ __forceinline__ float gelu_f(float h) {
  const float u = 0.70710678118654752f * h;
  const float a = fabsf(u);
  const float t = __builtin_amdgcn_rcpf(fmaf(0.3275911f, a, 1.0f));
  const float e = __expf(-a * a);
  float p = fmaf(1.061405429f, t, -1.453152027f);
  p = fmaf(p, t, 1.421413741f);
  p = fmaf(p, t, -0.284496736f);
  p = fmaf(p, t, 0.254829592f);
  p *= t;
  const float erfa = fmaf(-p, e, 1.0f);
  const float erfu = copysignf(erfa, u);
  return 0.5f * h * (1.0f + erfu);
}

// ---------------- prep: w1 [512][256] f32 -> bf16 packed [(k>>3)][n][k&7] ----------------
__global__ void prep_w1(const float* __restrict__ w1, unsigned short* __restrict__ w1p) {
  int idx = blockIdx.x * 256 + threadIdx.x;   // 0..131071
  int k = idx >> 8, n = idx & 255;
  w1p[((k >> 3) << 11) + (n << 3) + (k & 7)] = (unsigned short)f2bf(w1[idx]);
}

// ---------------- fused: LN -> bf16 MFMA GEMM -> GELU -> s -> per-(block,seg) partial pool ----
// Block: 32 rows, 256 threads (4 waves), ~33.5KB LDS -> 4 blocks/CU (16 waves/CU).
__global__ __launch_bounds__(256, 4) void fused_kernel(
    const float* __restrict__ feats, const float* __restrict__ ln_w,
    const float* __restrict__ ln_b, const unsigned short* __restrict__ w1p,
    const float* __restrict__ b1, const float* __restrict__ w2,
    const float* __restrict__ b2, const int* __restrict__ offs,
    float* __restrict__ m_arr, float* __restrict__ z_arr,
    int* __restrict__ seg_arr, float* __restrict__ Pp) {
  __shared__ __align__(16) unsigned short xs[RB * 512];  // 32KB bf16 x-tile, XOR-swizzled
  __shared__ float sred[4][RB];
  __shared__ float e_all[RB];
  __shared__ float sh_m[64];
  __shared__ int sh_bound[66];
  __shared__ int sh_meta[3];  // nparts, part_base, seg0
  char* xsb = (char*)xs;
  const int tid = threadIdx.x;
  const int lane = tid & 63;
  const int wid = tid >> 6;
  const long row0 = (long)blockIdx.x * RB;

  // ---- part bookkeeping (thread 0; 63 iterations, overlaps wave 1-3 LN) ----
  if (tid == 0) {
    const int r0i = (int)row0;
    int ncut = 0, pbase = blockIdx.x, seg0 = 0;
    sh_bound[0] = 0;
    for (int j = 1; j < NSEG; ++j) {
      const int c = offs[j];
      if (c <= r0i) { ++seg0; if (c & (RB - 1)) ++pbase; }
      else if (c < r0i + RB) { sh_bound[++ncut] = c - r0i; }
    }
    sh_bound[ncut + 1] = RB;
    sh_meta[0] = ncut + 1; sh_meta[1] = pbase; sh_meta[2] = seg0;
  }

  // ---- Phase 1: LayerNorm, 8 rows per wave, write bf16 x to LDS ----
  const int c0 = lane * 4;
  const float4 lw0 = *(const float4*)(ln_w + c0);
  const float4 lw1 = *(const float4*)(ln_w + 256 + c0);
  const float4 lb0 = *(const float4*)(ln_b + c0);
  const float4 lb1 = *(const float4*)(ln_b + 256 + c0);

  #pragma unroll 4
  for (int rr = 0; rr < 8; ++rr) {
    const int row = wid * 8 + rr;
    const float* rp = feats + (row0 + row) * 512;
    const float4 v0 = *(const float4*)(rp + c0);
    const float4 v1 = *(const float4*)(rp + 256 + c0);
    float sum = (v0.x + v0.y) + (v0.z + v0.w) + (v1.x + v1.y) + (v1.z + v1.w);
    float sq  = v0.x * v0.x + v0.y * v0.y + v0.z * v0.z + v0.w * v0.w
              + v1.x * v1.x + v1.y * v1.y + v1.z * v1.z + v1.w * v1.w;
    #pragma unroll
    for (int off = 32; off >= 1; off >>= 1) {
      sum += __shfl_xor(sum, off);
      sq  += __shfl_xor(sq, off);
    }
    const float mean = sum * (1.0f / 512.0f);
    const float var  = sq * (1.0f / 512.0f) - mean * mean;
    const float rstd = rsqrtf(var + 1e-5f);
    const float x0 = (v0.x - mean) * rstd * lw0.x + lb0.x;
    const float x1 = (v0.y - mean) * rstd * lw0.y + lb0.y;
    const float x2 = (v0.z - mean) * rstd * lw0.z + lb0.z;
    const float x3 = (v0.w - mean) * rstd * lw0.w + lb0.w;
    const float y0 = (v1.x - mean) * rstd * lw1.x + lb1.x;
    const float y1 = (v1.y - mean) * rstd * lw1.y + lb1.y;
    const float y2 = (v1.z - mean) * rstd * lw1.z + lb1.z;
    const float y3 = (v1.w - mean) * rstd * lw1.w + lb1.w;
    const unsigned int p0 = f2bf(x0) | (f2bf(x1) << 16);
    const unsigned int p1 = f2bf(x2) | (f2bf(x3) << 16);
    const unsigned int p2 = f2bf(y0) | (f2bf(y1) << 16);
    const unsigned int p3 = f2bf(y2) | (f2bf(y3) << 16);
    const unsigned int a0 = ((unsigned int)(row * 1024 + c0 * 2)) ^ (((unsigned int)(row & 7)) << 4);
    const unsigned int a1 = ((unsigned int)(row * 1024 + 512 + c0 * 2)) ^ (((unsigned int)(row & 7)) << 4);
    *(uint2*)(xsb + a0) = make_uint2(p0, p1);
    *(uint2*)(xsb + a1) = make_uint2(p2, p3);
  }
  __syncthreads();

  // ---- Phase 2: GEMM  h[32x256] = x[32x512] @ w1; wave owns 64 N-cols ----
  const int l15 = lane & 15, l4 = lane >> 4;
  const int nb = wid * 64;
  f32x4 acc[2][4];
  #pragma unroll
  for (int i = 0; i < 2; ++i)
    #pragma unroll
    for (int j = 0; j < 4; ++j)
      acc[i][j] = f32x4{0.f, 0.f, 0.f, 0.f};

  #pragma unroll 4
  for (int ks = 0; ks < 16; ++ks) {
    bf16x8 av[2], bv[4];
    #pragma unroll
    for (int mt = 0; mt < 2; ++mt) {
      const int row = mt * 16 + l15;
      const unsigned int ad =
          ((unsigned int)(row * 1024 + ks * 64 + l4 * 16)) ^ (((unsigned int)(row & 7)) << 4);
      av[mt] = *(const bf16x8*)(xsb + ad);
    }
    #pragma unroll
    for (int nt = 0; nt < 4; ++nt) {
      const int idx = (((ks * 4 + l4) << 8) + nb + nt * 16 + l15) << 3;
      bv[nt] = *(const bf16x8*)(w1p + idx);
    }
    #pragma unroll
    for (int mt = 0; mt < 2; ++mt)
      #pragma unroll
      for (int nt = 0; nt < 4; ++nt)
        acc[mt][nt] = __builtin_amdgcn_mfma_f32_16x16x32_bf16(av[mt], bv[nt], acc[mt][nt], 0, 0, 0);
  }

  // ---- Epilogue: s_row = sum_n gelu(acc + b1) * w2 ----
  float b1v[4], w2v[4];
  #pragma unroll
  for (int nt = 0; nt < 4; ++nt) {
    const int n = nb + nt * 16 + l15;
    b1v[nt] = b1[n];
    w2v[nt] = w2[n];
  }
  #pragma unroll
  for (int mt = 0; mt < 2; ++mt) {
    #pragma unroll
    for (int r = 0; r < 4; ++r) {
      float v = 0.0f;
      #pragma unroll
      for (int nt = 0; nt < 4; ++nt) {
        const float h = acc[mt][nt][r] + b1v[nt];
        v += gelu_f(h) * w2v[nt];
      }
      v += __shfl_xor(v, 1);
      v += __shfl_xor(v, 2);
      v += __shfl_xor(v, 4);
      v += __shfl_xor(v, 8);
      if (l15 == 0) sred[wid][mt * 16 + l4 * 4 + r] = v;
    }
  }
  __syncthreads();

  // ---- Phase 3 (wave 0): per-part m_loc, z_loc, e[row]; lanes >= RB masked ----
  if (wid == 0) {
    const int npart = sh_meta[0], pbase = sh_meta[1], seg0 = sh_meta[2];
    const bool valid = lane < RB;
    const float sv = valid
        ? (sred[0][lane] + sred[1][lane] + sred[2][lane] + sred[3][lane] + b2[0])
        : -INFINITY;
    int pid = 0;
    for (int i = 1; i < npart; ++i) pid += (sh_bound[i] <= lane) ? 1 : 0;
    if (!valid) pid = npart - 1;
    float mym = -INFINITY;
    for (int k = 0; k < npart; ++k) {
      float v = (pid == k) ? sv : -INFINITY;
      #pragma unroll
      for (int off = 32; off >= 1; off >>= 1) v = fmaxf(v, __shfl_xor(v, off));
      if (pid == k) mym = v;
      if (lane == 0) sh_m[k] = v;
    }
    const float e = __expf(sv - mym);  // lanes >= RB: exp(-inf - m) = 0
    if (valid) e_all[lane] = e;
    for (int k = 0; k < npart; ++k) {
      float v = (pid == k) ? e : 0.0f;
      #pragma unroll
      for (int off = 32; off >= 1; off >>= 1) v += __shfl_xor(v, off);
      if (lane == 0) {
        m_arr[pbase + k] = sh_m[k];
        z_arr[pbase + k] = v;
        seg_arr[pbase + k] = seg0 + k;
      }
    }
  }
  __syncthreads();

  // ---- Phase 4: partial pool P[c] = sum_rows e[r] * feats[r][c]  (L2-hot re-read) ----
  {
    const int pbase = sh_meta[1];
    const float2* f2p = (const float2*)feats + (size_t)row0 * 256;
    float2* Pp2 = (float2*)Pp;
    float2 pacc = make_float2(0.f, 0.f);
    int k = 0;
    #pragma unroll 4
    for (int r = 0; r < RB; ++r) {
      if (r == sh_bound[k + 1]) {
        Pp2[(size_t)(pbase + k) * 256 + tid] = pacc;
        pacc.x = 0.f; pacc.y = 0.f;
        ++k;
      }
      const float e = e_all[r];
      const float2 f = f2p[(size_t)r * 256 + tid];
      pacc.x += e * f.x;
      pacc.y += e * f.y;
    }
    Pp2[(size_t)(pbase + k) * 256 + tid] = pacc;
  }
}

// ---------------- combine: per segment, merge partials (exact two-level softmax) ----------------
// Fully parallel: no serial thread-0 loops. Parts of a segment are contiguous by construction.
__global__ __launch_bounds__(512) void combine_kernel(
    const int* __restrict__ offs, const float* __restrict__ m_arr,
    const float* __restrict__ z_arr, const int* __restrict__ seg_arr,
    const float* __restrict__ Pp, float* __restrict__ out) {
  const int b = blockIdx.x;
  const int tid = threadIdx.x;
  const int lane = tid & 63, wid = tid >> 6;
  __shared__ int s_lo, s_hi, s_ptot;
  __shared__ float redM[8], redZ[8];

  if (tid == 0) {
    int Ptot = NBLK;
    for (int j = 1; j < NSEG; ++j) Ptot += (offs[j] & (RB - 1)) ? 1 : 0;
    s_ptot = Ptot;
    s_lo = 1 << 30; s_hi = -1;
  }
  __syncthreads();
  const int Ptot = s_ptot;

  int llo = 1 << 30, lhi = -1;
  for (int p = tid; p < Ptot; p += 512) {
    if (seg_arr[p] == b) { llo = min(llo, p); lhi = max(lhi, p); }
  }
  atomicMin(&s_lo, llo);
  atomicMax(&s_hi, lhi);
  __syncthreads();
  const int lo = s_lo, hi = s_hi;

  // parallel max over parts
  float lm = -INFINITY;
  for (int p = lo + tid; p <= hi; p += 512) lm = fmaxf(lm, m_arr[p]);
  #pragma unroll
  for (int off = 32; off >= 1; off >>= 1) lm = fmaxf(lm, __shfl_xor(lm, off));
  if (lane == 0) redM[wid] = lm;
  __syncthreads();
  float M = redM[0];
  #pragma unroll
  for (int w = 1; w < 8; ++w) M = fmaxf(M, redM[w]);

  // parallel Z (deterministic fixed-tree reduce)
  float lz = 0.0f;
  for (int p = lo + tid; p <= hi; p += 512) lz += z_arr[p] * __expf(m_arr[p] - M);
  #pragma unroll
  for (int off = 32; off >= 1; off >>= 1) lz += __shfl_xor(lz, off);
  if (lane == 0) redZ[wid] = lz;
  __syncthreads();
  float Z = 0.0f;
  #pragma unroll
  for (int w = 0; w < 8; ++w) Z += redZ[w];
  const float invZ = 1.0f / Z;

  // coalesced accumulate; per-part scale recomputed on the fly (broadcast loads, cheap)
  float acc = 0.0f;
  for (int p = lo; p <= hi; ++p)
    acc += __expf(m_arr[p] - M) * Pp[(size_t)p * 512 + tid];
  out[b * 512 + tid] = acc * invZ;
}

extern "C" void kernel_launch(void* const* d_in, const int* in_sizes, int n_in,
                              void* d_out, int out_size, void* d_ws, size_t ws_size,
                              hipStream_t stream) {
  const float* feats = (const float*)d_in[0];
  const float* ln_w  = (const float*)d_in[1];
  const float* ln_b  = (const float*)d_in[2];
  const float* w1    = (const float*)d_in[3];
  const float* b1    = (const float*)d_in[4];
  const float* w2    = (const float*)d_in[5];
  const float* b2    = (const float*)d_in[6];
  const int* offs    = (const int*)d_in[7];
  float* out = (float*)d_out;

  char* ws = (char*)d_ws;
  unsigned short* w1p = (unsigned short*)(ws);                 // 256 KB
  float* m_arr  = (float*)(ws + 262144);                       // MAXP floats
  float* z_arr  = (float*)(ws + 262144 + 131072);
  int*   seg_arr= (int*)  (ws + 262144 + 262144);
  float* Pp     = (float*)(ws + 262144 + 393216);              // MAXP * 512 f32 (~33.7 MB)

  prep_w1<<<512, 256, 0, stream>>>(w1, w1p);
  fused_kernel<<<NBLK, 256, 0, stream>>>(feats, ln_w, ln_b, w1p, b1, w2, b2, offs,
                                         m_arr, z_arr, seg_arr, Pp);
  combine_kernel<<<NSEG, 512, 0, stream>>>(offs, m_arr, z_arr, seg_arr, Pp, out);
}

// Round 4
// 916.833 us; speedup vs baseline: 1.2458x; 1.2458x over previous
//
#include <hip/hip_runtime.h>

#define NPTS 524288
#define NSEG 64
#define RB 64                   // rows per block
#define NBLK (NPTS / RB)        // 8192 blocks
#define MAXP (NBLK + NSEG)      // max part records

typedef __bf16 bf16x8 __attribute__((ext_vector_type(8)));
typedef float f32x4 __attribute__((ext_vector_type(4)));

__device__ __forceinline__ unsigned int f2bf(float f) {
  unsigned int u = __float_as_uint(f);
  return (u + 0x7FFFu + ((u >> 16) & 1u)) >> 16;  // RNE bf16
}

// Branchless erf, Abramowitz-Stegun 7.1.26, |err| <= 1.5e-7
__device__ __forceinline__ float gelu_f(float h) {
  const float u = 0.70710678118654752f * h;
  const float a = fabsf(u);
  const float t = __builtin_amdgcn_rcpf(fmaf(0.3275911f, a, 1.0f));
  const float e = __expf(-a * a);
  float p = fmaf(1.061405429f, t, -1.453152027f);
  p = fmaf(p, t, 1.421413741f);
  p = fmaf(p, t, -0.284496736f);
  p = fmaf(p, t, 0.254829592f);
  p *= t;
  const float erfa = fmaf(-p, e, 1.0f);
  const float erfu = copysignf(erfa, u);
  return 0.5f * h * (1.0f + erfu);
}

// ---------------- prep: w1 [512][256] f32 -> bf16 packed [(k>>3)][n][k&7] ----------------
__global__ void prep_w1(const float* __restrict__ w1, unsigned short* __restrict__ w1p) {
  int idx = blockIdx.x * 256 + threadIdx.x;   // 0..131071
  int k = idx >> 8, n = idx & 255;
  w1p[((k >> 3) << 11) + (n << 3) + (k & 7)] = (unsigned short)f2bf(w1[idx]);
}

// ---------------- fused: LN -> bf16 MFMA GEMM -> GELU -> s -> per-(block,seg) partial pool ----
// Block: 64 rows, 512 threads (8 waves). 64KB LDS -> 2 blocks/CU = 16 waves/CU.
// GEMM is N-split: wave w owns cols [w*32, w*32+32) so w1p traffic/block stays 256KB.
__global__ __launch_bounds__(512, 4) void fused_kernel(
    const float* __restrict__ feats, const float* __restrict__ ln_w,
    const float* __restrict__ ln_b, const unsigned short* __restrict__ w1p,
    const float* __restrict__ b1, const float* __restrict__ w2,
    const float* __restrict__ b2, const int* __restrict__ offs,
    float* __restrict__ m_arr, float* __restrict__ z_arr,
    float* __restrict__ Pp) {
  __shared__ __align__(16) unsigned short xs[RB * 512];  // 64KB bf16 x-tile, XOR-swizzled
  __shared__ float sred[8][RB];
  __shared__ float e_all[RB];
  __shared__ float sh_m[64];
  __shared__ int sh_bound[66];
  __shared__ int sh_meta[3];  // nparts, part_base, seg0
  char* xsb = (char*)xs;
  const int tid = threadIdx.x;
  const int lane = tid & 63;
  const int wid = tid >> 6;
  const long row0 = (long)blockIdx.x * RB;

  // ---- part bookkeeping: wave 0, ballot-based (no serial loop) ----
  if (wid == 0) {
    const int r0i = (int)row0;
    const int c = offs[lane + 1];  // lanes 0..63 -> offs[1..64]; offs[64]=NPTS is never <= r0i
    const bool before = (c <= r0i);
    const unsigned long long mb = __ballot(before && (c & (RB - 1)));
    const unsigned long long ms = __ballot(before);
    const unsigned long long mi = __ballot((c > r0i) && (c < r0i + RB));
    if ((c > r0i) && (c < r0i + RB)) {
      const int rank = __popcll(mi & ((1ull << lane) - 1ull));
      sh_bound[rank + 1] = c - r0i;
    }
    if (lane == 0) {
      const int npart = __popcll(mi) + 1;
      sh_bound[0] = 0;
      sh_bound[npart] = RB;
      sh_meta[0] = npart;
      sh_meta[1] = blockIdx.x + __popcll(mb);
      sh_meta[2] = __popcll(ms);
    }
  }

  // ---- Phase 1: LayerNorm, 8 rows per wave, write bf16 x to LDS ----
  const int c0 = lane * 4;
  const float4 lw0 = *(const float4*)(ln_w + c0);
  const float4 lw1 = *(const float4*)(ln_w + 256 + c0);
  const float4 lb0 = *(const float4*)(ln_b + c0);
  const float4 lb1 = *(const float4*)(ln_b + 256 + c0);

  #pragma unroll
  for (int rr = 0; rr < 8; ++rr) {
    const int row = wid * 8 + rr;
    const float* rp = feats + (row0 + row) * 512;
    const float4 v0 = *(const float4*)(rp + c0);
    const float4 v1 = *(const float4*)(rp + 256 + c0);
    float sum = (v0.x + v0.y) + (v0.z + v0.w) + (v1.x + v1.y) + (v1.z + v1.w);
    float sq  = v0.x * v0.x + v0.y * v0.y + v0.z * v0.z + v0.w * v0.w
              + v1.x * v1.x + v1.y * v1.y + v1.z * v1.z + v1.w * v1.w;
    #pragma unroll
    for (int off = 32; off >= 1; off >>= 1) {
      sum += __shfl_xor(sum, off);
      sq  += __shfl_xor(sq, off);
    }
    const float mean = sum * (1.0f / 512.0f);
    const float var  = sq * (1.0f / 512.0f) - mean * mean;
    const float rstd = rsqrtf(var + 1e-5f);
    const float x0 = (v0.x - mean) * rstd * lw0.x + lb0.x;
    const float x1 = (v0.y - mean) * rstd * lw0.y + lb0.y;
    const float x2 = (v0.z - mean) * rstd * lw0.z + lb0.z;
    const float x3 = (v0.w - mean) * rstd * lw0.w + lb0.w;
    const float y0 = (v1.x - mean) * rstd * lw1.x + lb1.x;
    const float y1 = (v1.y - mean) * rstd * lw1.y + lb1.y;
    const float y2 = (v1.z - mean) * rstd * lw1.z + lb1.z;
    const float y3 = (v1.w - mean) * rstd * lw1.w + lb1.w;
    const unsigned int p0 = f2bf(x0) | (f2bf(x1) << 16);
    const unsigned int p1 = f2bf(x2) | (f2bf(x3) << 16);
    const unsigned int p2 = f2bf(y0) | (f2bf(y1) << 16);
    const unsigned int p3 = f2bf(y2) | (f2bf(y3) << 16);
    const unsigned int a0 = ((unsigned int)(row * 1024 + c0 * 2)) ^ (((unsigned int)(row & 7)) << 4);
    const unsigned int a1 = ((unsigned int)(row * 1024 + 512 + c0 * 2)) ^ (((unsigned int)(row & 7)) << 4);
    *(uint2*)(xsb + a0) = make_uint2(p0, p1);
    *(uint2*)(xsb + a1) = make_uint2(p2, p3);
  }
  __syncthreads();

  // ---- Phase 2: GEMM  h[64x256] = x[64x512] @ w1; wave owns 32 N-cols ----
  const int l15 = lane & 15, l4 = lane >> 4;
  const int nb = wid * 32;
  f32x4 acc[4][2];
  #pragma unroll
  for (int i = 0; i < 4; ++i)
    #pragma unroll
    for (int j = 0; j < 2; ++j)
      acc[i][j] = f32x4{0.f, 0.f, 0.f, 0.f};

  #pragma unroll 4
  for (int ks = 0; ks < 16; ++ks) {
    bf16x8 av[4], bv[2];
    #pragma unroll
    for (int mt = 0; mt < 4; ++mt) {
      const int row = mt * 16 + l15;
      const unsigned int ad =
          ((unsigned int)(row * 1024 + ks * 64 + l4 * 16)) ^ (((unsigned int)(row & 7)) << 4);
      av[mt] = *(const bf16x8*)(xsb + ad);
    }
    #pragma unroll
    for (int nt = 0; nt < 2; ++nt) {
      const int idx = (((ks * 4 + l4) << 8) + nb + nt * 16 + l15) << 3;
      bv[nt] = *(const bf16x8*)(w1p + idx);
    }
    #pragma unroll
    for (int mt = 0; mt < 4; ++mt)
      #pragma unroll
      for (int nt = 0; nt < 2; ++nt)
        acc[mt][nt] = __builtin_amdgcn_mfma_f32_16x16x32_bf16(av[mt], bv[nt], acc[mt][nt], 0, 0, 0);
  }

  // ---- Epilogue: s_row = sum_n gelu(acc + b1) * w2 ----
  float b1v[2], w2v[2];
  #pragma unroll
  for (int nt = 0; nt < 2; ++nt) {
    const int n = nb + nt * 16 + l15;
    b1v[nt] = b1[n];
    w2v[nt] = w2[n];
  }
  #pragma unroll
  for (int mt = 0; mt < 4; ++mt) {
    #pragma unroll
    for (int r = 0; r < 4; ++r) {
      float v = 0.0f;
      #pragma unroll
      for (int nt = 0; nt < 2; ++nt) {
        const float h = acc[mt][nt][r] + b1v[nt];
        v += gelu_f(h) * w2v[nt];
      }
      v += __shfl_xor(v, 1);
      v += __shfl_xor(v, 2);
      v += __shfl_xor(v, 4);
      v += __shfl_xor(v, 8);
      if (l15 == 0) sred[wid][mt * 16 + l4 * 4 + r] = v;
    }
  }
  __syncthreads();

  // ---- Phase 3 (wave 0): per-part m_loc, z_loc, e[row] ----
  if (wid == 0) {
    const int npart = sh_meta[0], pbase = sh_meta[1];
    float sv = b2[0];
    #pragma unroll
    for (int w = 0; w < 8; ++w) sv += sred[w][lane];
    int pid = 0;
    for (int i = 1; i < npart; ++i) pid += (sh_bound[i] <= lane) ? 1 : 0;
    float mym = -INFINITY;
    for (int k = 0; k < npart; ++k) {
      float v = (pid == k) ? sv : -INFINITY;
      #pragma unroll
      for (int off = 32; off >= 1; off >>= 1) v = fmaxf(v, __shfl_xor(v, off));
      if (pid == k) mym = v;
      if (lane == 0) sh_m[k] = v;
    }
    const float e = __expf(sv - mym);
    e_all[lane] = e;
    for (int k = 0; k < npart; ++k) {
      float v = (pid == k) ? e : 0.0f;
      #pragma unroll
      for (int off = 32; off >= 1; off >>= 1) v += __shfl_xor(v, off);
      if (lane == 0) {
        m_arr[pbase + k] = sh_m[k];
        z_arr[pbase + k] = v;
      }
    }
  }
  __syncthreads();

  // ---- Phase 4: partial pool P[c] = sum_rows e[r] * feats[r][c]  (L2-hot re-read) ----
  // 512 threads: thread owns f32 column `tid`.
  {
    const int pbase = sh_meta[1];
    const float* fp = feats + (size_t)row0 * 512;
    float pacc = 0.0f;
    int k = 0;
    #pragma unroll 4
    for (int r = 0; r < RB; ++r) {
      if (r == sh_bound[k + 1]) {
        Pp[(size_t)(pbase + k) * 512 + tid] = pacc;
        pacc = 0.0f;
        ++k;
      }
      pacc += e_all[r] * fp[(size_t)r * 512 + tid];
    }
    Pp[(size_t)(pbase + k) * 512 + tid] = pacc;
  }
}

// ---------------- combine: per segment, merge partials (exact two-level softmax) ----------------
// Part range per segment is closed-form: P_start(b) = (offs[b]>>6) + #{j<=b: offs[j]&63 != 0}.
__global__ __launch_bounds__(512) void combine_kernel(
    const int* __restrict__ offs, const float* __restrict__ m_arr,
    const float* __restrict__ z_arr, const float* __restrict__ Pp,
    float* __restrict__ out) {
  const int b = blockIdx.x;
  const int tid = threadIdx.x;
  const int lane = tid & 63, wid = tid >> 6;
  __shared__ int s_lohi[2];
  __shared__ float redM[8], redZ[8];

  if (wid == 0) {
    const int c = offs[lane + 1];  // lanes 0..63 -> offs[1..64]
    const unsigned long long nal = __ballot((c & (RB - 1)) != 0);
    if (lane == 0) {
      const unsigned long long mlo = (b == 0) ? 0ull : ((1ull << b) - 1ull);
      const unsigned long long mhi = (b == 63) ? ~0ull : ((1ull << (b + 1)) - 1ull);
      s_lohi[0] = (offs[b] >> 6) + __popcll(nal & mlo);
      s_lohi[1] = (offs[b + 1] >> 6) + __popcll(nal & mhi) - 1;
    }
  }
  __syncthreads();
  const int lo = s_lohi[0], hi = s_lohi[1];

  // parallel max over parts
  float lm = -INFINITY;
  for (int p = lo + tid; p <= hi; p += 512) lm = fmaxf(lm, m_arr[p]);
  #pragma unroll
  for (int off = 32; off >= 1; off >>= 1) lm = fmaxf(lm, __shfl_xor(lm, off));
  if (lane == 0) redM[wid] = lm;
  __syncthreads();
  float M = redM[0];
  #pragma unroll
  for (int w = 1; w < 8; ++w) M = fmaxf(M, redM[w]);

  // parallel Z (deterministic fixed-tree reduce)
  float lz = 0.0f;
  for (int p = lo + tid; p <= hi; p += 512) lz += z_arr[p] * __expf(m_arr[p] - M);
  #pragma unroll
  for (int off = 32; off >= 1; off >>= 1) lz += __shfl_xor(lz, off);
  if (lane == 0) redZ[wid] = lz;
  __syncthreads();
  float Z = 0.0f;
  #pragma unroll
  for (int w = 0; w < 8; ++w) Z += redZ[w];
  const float invZ = 1.0f / Z;

  // coalesced accumulate; per-part scale recomputed on the fly (broadcast loads)
  float acc = 0.0f;
  for (int p = lo; p <= hi; ++p)
    acc += __expf(m_arr[p] - M) * Pp[(size_t)p * 512 + tid];
  out[b * 512 + tid] = acc * invZ;
}

extern "C" void kernel_launch(void* const* d_in, const int* in_sizes, int n_in,
                              void* d_out, int out_size, void* d_ws, size_t ws_size,
                              hipStream_t stream) {
  const float* feats = (const float*)d_in[0];
  const float* ln_w  = (const float*)d_in[1];
  const float* ln_b  = (const float*)d_in[2];
  const float* w1    = (const float*)d_in[3];
  const float* b1    = (const float*)d_in[4];
  const float* w2    = (const float*)d_in[5];
  const float* b2    = (const float*)d_in[6];
  const int* offs    = (const int*)d_in[7];
  float* out = (float*)d_out;

  char* ws = (char*)d_ws;
  unsigned short* w1p = (unsigned short*)(ws);                 // 256 KB
  float* m_arr  = (float*)(ws + 262144);                       // MAXP f32
  float* z_arr  = (float*)(ws + 393216);                       // MAXP f32
  float* Pp     = (float*)(ws + 524288);                       // MAXP * 512 f32 (~16.9 MB)

  prep_w1<<<512, 256, 0, stream>>>(w1, w1p);
  fused_kernel<<<NBLK, 512, 0, stream>>>(feats, ln_w, ln_b, w1p, b1, w2, b2, offs,
                                         m_arr, z_arr, Pp);
  combine_kernel<<<NSEG, 512, 0, stream>>>(offs, m_arr, z_arr, Pp, out);
}

// Round 5
// 714.086 us; speedup vs baseline: 1.5995x; 1.2839x over previous
//
#include <hip/hip_runtime.h>

#define NPTS 524288
#define NSEG 64
#define RB 64                    // rows per score block
#define CB 256                   // rows per pool block
#define NPB (NPTS / CB)          // 2048 pool blocks
#define MAXP2 (NPB + NSEG)       // max pool part records (2112)

typedef __bf16 bf16x8 __attribute__((ext_vector_type(8)));
typedef float f32x4 __attribute__((ext_vector_type(4)));

__device__ __forceinline__ unsigned int f2bf(float f) {
  unsigned int u = __float_as_uint(f);
  return (u + 0x7FFFu + ((u >> 16) & 1u)) >> 16;  // RNE bf16
}

// Branchless erf, Abramowitz-Stegun 7.1.26, |err| <= 1.5e-7
__device__ __forceinline__ float gelu_f(float h) {
  const float u = 0.70710678118654752f * h;
  const float a = fabsf(u);
  const float t = __builtin_amdgcn_rcpf(fmaf(0.3275911f, a, 1.0f));
  const float e = __expf(-a * a);
  float p = fmaf(1.061405429f, t, -1.453152027f);
  p = fmaf(p, t, 1.421413741f);
  p = fmaf(p, t, -0.284496736f);
  p = fmaf(p, t, 0.254829592f);
  p *= t;
  const float erfa = fmaf(-p, e, 1.0f);
  const float erfu = copysignf(erfa, u);
  return 0.5f * h * (1.0f + erfu);
}

// ---------------- prep: w1 [512][256] f32 -> bf16 packed [(k>>3)][n][k&7] ----------------
// 64 blocks x 256 threads; each thread packs 8 k-values for one n -> one 16B store.
__global__ void prep_w1(const float* __restrict__ w1, unsigned short* __restrict__ w1p) {
  const int n = threadIdx.x;         // 0..255
  const int k0 = blockIdx.x * 8;     // 0..504
  unsigned int d[4];
  #pragma unroll
  for (int j = 0; j < 4; ++j) {
    const unsigned int lo = f2bf(w1[(size_t)(k0 + 2 * j) * 256 + n]);
    const unsigned int hi = f2bf(w1[(size_t)(k0 + 2 * j + 1) * 256 + n]);
    d[j] = lo | (hi << 16);
  }
  uint4* dst = (uint4*)(w1p + (size_t)blockIdx.x * 2048 + n * 8);
  *dst = make_uint4(d[0], d[1], d[2], d[3]);
}

// ---------------- score: LN -> bf16 MFMA GEMM -> GELU -> s[N] ----------------
// Block: 64 rows, 512 threads (8 waves). 64KB LDS -> 2 blocks/CU = 16 waves/CU.
__global__ __launch_bounds__(512, 4) void score_kernel(
    const float* __restrict__ feats, const float* __restrict__ ln_w,
    const float* __restrict__ ln_b, const unsigned short* __restrict__ w1p,
    const float* __restrict__ b1, const float* __restrict__ w2,
    const float* __restrict__ b2, float* __restrict__ s_out) {
  __shared__ __align__(16) unsigned short xs[RB * 512];  // 64KB bf16 x-tile, XOR-swizzled
  __shared__ float sred[8][RB];
  char* xsb = (char*)xs;
  const int tid = threadIdx.x;
  const int lane = tid & 63;
  const int wid = tid >> 6;
  const long row0 = (long)blockIdx.x * RB;

  // ---- Phase 1: LayerNorm, 8 rows per wave, write bf16 x to LDS ----
  const int c0 = lane * 4;
  const float4 lw0 = *(const float4*)(ln_w + c0);
  const float4 lw1 = *(const float4*)(ln_w + 256 + c0);
  const float4 lb0 = *(const float4*)(ln_b + c0);
  const float4 lb1 = *(const float4*)(ln_b + 256 + c0);

  #pragma unroll
  for (int rr = 0; rr < 8; ++rr) {
    const int row = wid * 8 + rr;
    const float* rp = feats + (row0 + row) * 512;
    const float4 v0 = *(const float4*)(rp + c0);
    const float4 v1 = *(const float4*)(rp + 256 + c0);
    float sum = (v0.x + v0.y) + (v0.z + v0.w) + (v1.x + v1.y) + (v1.z + v1.w);
    float sq  = v0.x * v0.x + v0.y * v0.y + v0.z * v0.z + v0.w * v0.w
              + v1.x * v1.x + v1.y * v1.y + v1.z * v1.z + v1.w * v1.w;
    #pragma unroll
    for (int off = 32; off >= 1; off >>= 1) {
      sum += __shfl_xor(sum, off);
      sq  += __shfl_xor(sq, off);
    }
    const float mean = sum * (1.0f / 512.0f);
    const float var  = sq * (1.0f / 512.0f) - mean * mean;
    const float rstd = rsqrtf(var + 1e-5f);
    const float x0 = (v0.x - mean) * rstd * lw0.x + lb0.x;
    const float x1 = (v0.y - mean) * rstd * lw0.y + lb0.y;
    const float x2 = (v0.z - mean) * rstd * lw0.z + lb0.z;
    const float x3 = (v0.w - mean) * rstd * lw0.w + lb0.w;
    const float y0 = (v1.x - mean) * rstd * lw1.x + lb1.x;
    const float y1 = (v1.y - mean) * rstd * lw1.y + lb1.y;
    const float y2 = (v1.z - mean) * rstd * lw1.z + lb1.z;
    const float y3 = (v1.w - mean) * rstd * lw1.w + lb1.w;
    const unsigned int p0 = f2bf(x0) | (f2bf(x1) << 16);
    const unsigned int p1 = f2bf(x2) | (f2bf(x3) << 16);
    const unsigned int p2 = f2bf(y0) | (f2bf(y1) << 16);
    const unsigned int p3 = f2bf(y2) | (f2bf(y3) << 16);
    const unsigned int a0 = ((unsigned int)(row * 1024 + c0 * 2)) ^ (((unsigned int)(row & 7)) << 4);
    const unsigned int a1 = ((unsigned int)(row * 1024 + 512 + c0 * 2)) ^ (((unsigned int)(row & 7)) << 4);
    *(uint2*)(xsb + a0) = make_uint2(p0, p1);
    *(uint2*)(xsb + a1) = make_uint2(p2, p3);
  }
  __syncthreads();

  // ---- Phase 2: GEMM  h[64x256] = x[64x512] @ w1; wave owns 32 N-cols ----
  const int l15 = lane & 15, l4 = lane >> 4;
  const int nb = wid * 32;
  f32x4 acc[4][2];
  #pragma unroll
  for (int i = 0; i < 4; ++i)
    #pragma unroll
    for (int j = 0; j < 2; ++j)
      acc[i][j] = f32x4{0.f, 0.f, 0.f, 0.f};

  #pragma unroll 4
  for (int ks = 0; ks < 16; ++ks) {
    bf16x8 av[4], bv[2];
    #pragma unroll
    for (int mt = 0; mt < 4; ++mt) {
      const int row = mt * 16 + l15;
      const unsigned int ad =
          ((unsigned int)(row * 1024 + ks * 64 + l4 * 16)) ^ (((unsigned int)(row & 7)) << 4);
      av[mt] = *(const bf16x8*)(xsb + ad);
    }
    #pragma unroll
    for (int nt = 0; nt < 2; ++nt) {
      const int idx = (((ks * 4 + l4) << 8) + nb + nt * 16 + l15) << 3;
      bv[nt] = *(const bf16x8*)(w1p + idx);
    }
    #pragma unroll
    for (int mt = 0; mt < 4; ++mt)
      #pragma unroll
      for (int nt = 0; nt < 2; ++nt)
        acc[mt][nt] = __builtin_amdgcn_mfma_f32_16x16x32_bf16(av[mt], bv[nt], acc[mt][nt], 0, 0, 0);
  }

  // ---- Epilogue: s_row = sum_n gelu(acc + b1) * w2 ----
  float b1v[2], w2v[2];
  #pragma unroll
  for (int nt = 0; nt < 2; ++nt) {
    const int n = nb + nt * 16 + l15;
    b1v[nt] = b1[n];
    w2v[nt] = w2[n];
  }
  #pragma unroll
  for (int mt = 0; mt < 4; ++mt) {
    #pragma unroll
    for (int r = 0; r < 4; ++r) {
      float v = 0.0f;
      #pragma unroll
      for (int nt = 0; nt < 2; ++nt) {
        const float h = acc[mt][nt][r] + b1v[nt];
        v += gelu_f(h) * w2v[nt];
      }
      v += __shfl_xor(v, 1);
      v += __shfl_xor(v, 2);
      v += __shfl_xor(v, 4);
      v += __shfl_xor(v, 8);
      if (l15 == 0) sred[wid][mt * 16 + l4 * 4 + r] = v;
    }
  }
  __syncthreads();
  if (wid == 0) {
    float sv = b2[0];
    #pragma unroll
    for (int w = 0; w < 8; ++w) sv += sred[w][lane];
    s_out[row0 + lane] = sv;
  }
}

// ---------------- seg_stats: per-segment max and 1/sum(exp) (s is L2-resident, 2MB) ----
__global__ void seg_stats(const float* __restrict__ s, const int* __restrict__ offs,
                          float* __restrict__ mz) {
  const int b = blockIdx.x;
  const int start = offs[b], end = offs[b + 1];
  const int tid = threadIdx.x;
  const int lane = tid & 63, wid = tid >> 6;
  __shared__ float red[4];

  float lm = -INFINITY;
  for (int i = start + tid; i < end; i += 256) lm = fmaxf(lm, s[i]);
  #pragma unroll
  for (int off = 32; off >= 1; off >>= 1) lm = fmaxf(lm, __shfl_xor(lm, off));
  if (lane == 0) red[wid] = lm;
  __syncthreads();
  const float m = fmaxf(fmaxf(red[0], red[1]), fmaxf(red[2], red[3]));
  __syncthreads();

  float ls = 0.0f;
  for (int i = start + tid; i < end; i += 256) ls += __expf(s[i] - m);
  #pragma unroll
  for (int off = 32; off >= 1; off >>= 1) ls += __shfl_xor(ls, off);
  if (lane == 0) red[wid] = ls;
  __syncthreads();
  if (tid == 0) {
    const float z = red[0] + red[1] + red[2] + red[3];
    mz[b] = m;
    mz[NSEG + b] = 1.0f / z;
  }
}

// ---------------- pool: streaming partial pool, final weights, no atomics ----------------
// Block = 256 rows x 512 threads (thread owns one f32 column). 4 independent FMA chains.
__global__ __launch_bounds__(512) void pool_kernel(
    const float* __restrict__ feats, const float* __restrict__ s,
    const float* __restrict__ mz, const int* __restrict__ offs,
    float* __restrict__ Pp) {
  __shared__ float sw[CB];
  __shared__ int sh_bound[66];
  __shared__ int sh_meta[3];  // npart, pbase, seg0
  const int tid = threadIdx.x;
  const int lane = tid & 63, wid = tid >> 6;
  const int r0 = blockIdx.x * CB;

  if (wid == 0) {
    const int c = offs[lane + 1];  // lanes 0..63 -> offs[1..64]
    const bool before = (c <= r0);
    const unsigned long long mb = __ballot(before && (c & (CB - 1)));
    const unsigned long long ms = __ballot(before);
    const unsigned long long mi = __ballot((c > r0) && (c < r0 + CB));
    if ((c > r0) && (c < r0 + CB)) {
      const int rank = __popcll(mi & ((1ull << lane) - 1ull));
      sh_bound[rank + 1] = c - r0;
    }
    if (lane == 0) {
      const int npart = __popcll(mi) + 1;
      sh_bound[0] = 0;
      sh_bound[npart] = CB;
      sh_meta[0] = npart;
      sh_meta[1] = blockIdx.x + __popcll(mb);
      sh_meta[2] = __popcll(ms);
    }
  }
  __syncthreads();
  const int npart = sh_meta[0], pbase = sh_meta[1], seg0 = sh_meta[2];

  // final per-row weights into LDS (threads 0..255)
  if (tid < CB) {
    int k = 0;
    for (int i = 1; i < npart; ++i) k += (sh_bound[i] <= tid) ? 1 : 0;
    sw[tid] = __expf(s[r0 + tid] - mz[seg0 + k]) * mz[NSEG + seg0 + k];
  }
  __syncthreads();

  const float* fp = feats + (size_t)r0 * 512;
  float a0 = 0.f, a1 = 0.f, a2 = 0.f, a3 = 0.f;
  int k = 0;
  #pragma unroll 4
  for (int r = 0; r < CB; ++r) {
    if (r == sh_bound[k + 1]) {          // wave-uniform, rare
      Pp[(size_t)(pbase + k) * 512 + tid] = (a0 + a1) + (a2 + a3);
      a0 = a1 = a2 = a3 = 0.f;
      ++k;
    }
    const float v = sw[r] * fp[(size_t)r * 512 + tid];
    if ((r & 3) == 0) a0 += v;
    else if ((r & 3) == 1) a1 += v;
    else if ((r & 3) == 2) a2 += v;
    else a3 += v;
  }
  Pp[(size_t)(pbase + k) * 512 + tid] = (a0 + a1) + (a2 + a3);
}

// ---------------- combine: out[b][c] = sum over b's parts of Pp[p][c] ----------------
__global__ __launch_bounds__(512) void combine_kernel(
    const int* __restrict__ offs, const float* __restrict__ Pp,
    float* __restrict__ out) {
  const int b = blockIdx.x;
  const int tid = threadIdx.x;
  const int lane = tid & 63, wid = tid >> 6;
  __shared__ int s_lohi[2];

  if (wid == 0) {
    const int c = offs[lane + 1];
    const unsigned long long nal = __ballot((c & (CB - 1)) != 0);
    if (lane == 0) {
      const unsigned long long mlo = (b == 0) ? 0ull : ((1ull << b) - 1ull);
      const unsigned long long mhi = (b == 63) ? ~0ull : ((1ull << (b + 1)) - 1ull);
      s_lohi[0] = (offs[b] >> 8) + __popcll(nal & mlo);
      s_lohi[1] = (offs[b + 1] >> 8) + __popcll(nal & mhi) - 1;
    }
  }
  __syncthreads();
  const int lo = s_lohi[0], hi = s_lohi[1];

  float a0 = 0.f, a1 = 0.f, a2 = 0.f, a3 = 0.f;
  int p = lo;
  for (; p + 3 <= hi; p += 4) {
    a0 += Pp[(size_t)p * 512 + tid];
    a1 += Pp[(size_t)(p + 1) * 512 + tid];
    a2 += Pp[(size_t)(p + 2) * 512 + tid];
    a3 += Pp[(size_t)(p + 3) * 512 + tid];
  }
  for (; p <= hi; ++p) a0 += Pp[(size_t)p * 512 + tid];
  out[b * 512 + tid] = (a0 + a1) + (a2 + a3);
}

extern "C" void kernel_launch(void* const* d_in, const int* in_sizes, int n_in,
                              void* d_out, int out_size, void* d_ws, size_t ws_size,
                              hipStream_t stream) {
  const float* feats = (const float*)d_in[0];
  const float* ln_w  = (const float*)d_in[1];
  const float* ln_b  = (const float*)d_in[2];
  const float* w1    = (const float*)d_in[3];
  const float* b1    = (const float*)d_in[4];
  const float* w2    = (const float*)d_in[5];
  const float* b2    = (const float*)d_in[6];
  const int* offs    = (const int*)d_in[7];
  float* out = (float*)d_out;

  char* ws = (char*)d_ws;
  unsigned short* w1p = (unsigned short*)(ws);                    // 256 KB
  float* s_buf = (float*)(ws + 262144);                           // 2 MB
  float* mz    = (float*)(ws + 262144 + 2097152);                 // 128 f32
  float* Pp    = (float*)(ws + 262144 + 2097152 + 4096);          // MAXP2*512 f32 (~4.3 MB)

  prep_w1<<<64, 256, 0, stream>>>(w1, w1p);
  score_kernel<<<NPTS / RB, 512, 0, stream>>>(feats, ln_w, ln_b, w1p, b1, w2, b2, s_buf);
  seg_stats<<<NSEG, 256, 0, stream>>>(s_buf, offs, mz);
  pool_kernel<<<NPB, 512, 0, stream>>>(feats, s_buf, mz, offs, Pp);
  combine_kernel<<<NSEG, 512, 0, stream>>>(offs, Pp, out);
}

// Round 6
// 679.212 us; speedup vs baseline: 1.6816x; 1.0513x over previous
//
#include <hip/hip_runtime.h>

#define NPTS 524288
#define NSEG 64
#define RB 64                    // rows per score block
#define CB 256                   // rows per pool block
#define NPB (NPTS / CB)          // 2048 pool blocks
#define MAXP2 (NPB + NSEG)       // max pool part records (2112)

typedef __bf16 bf16x8 __attribute__((ext_vector_type(8)));
typedef float f32x4 __attribute__((ext_vector_type(4)));

__device__ __forceinline__ unsigned int f2bf(float f) {
  unsigned int u = __float_as_uint(f);
  return (u + 0x7FFFu + ((u >> 16) & 1u)) >> 16;  // RNE bf16
}

// Branchless erf, Abramowitz-Stegun 7.1.26, |err| <= 1.5e-7
__device__ __forceinline__ float gelu_f(float h) {
  const float u = 0.70710678118654752f * h;
  const float a = fabsf(u);
  const float t = __builtin_amdgcn_rcpf(fmaf(0.3275911f, a, 1.0f));
  const float e = __expf(-a * a);
  float p = fmaf(1.061405429f, t, -1.453152027f);
  p = fmaf(p, t, 1.421413741f);
  p = fmaf(p, t, -0.284496736f);
  p = fmaf(p, t, 0.254829592f);
  p *= t;
  const float erfa = fmaf(-p, e, 1.0f);
  const float erfu = copysignf(erfa, u);
  return 0.5f * h * (1.0f + erfu);
}

// ---------------- prep: w1 [512][256] f32 -> bf16 packed [(k>>3)][n][k&7] ----------------
__global__ void prep_w1(const float* __restrict__ w1, unsigned short* __restrict__ w1p) {
  const int n = threadIdx.x;         // 0..255
  const int k0 = blockIdx.x * 8;     // 0..504
  unsigned int d[4];
  #pragma unroll
  for (int j = 0; j < 4; ++j) {
    const unsigned int lo = f2bf(w1[(size_t)(k0 + 2 * j) * 256 + n]);
    const unsigned int hi = f2bf(w1[(size_t)(k0 + 2 * j + 1) * 256 + n]);
    d[j] = lo | (hi << 16);
  }
  uint4* dst = (uint4*)(w1p + (size_t)blockIdx.x * 2048 + n * 8);
  *dst = make_uint4(d[0], d[1], d[2], d[3]);
}

// ---------------- score: LN -> bf16 MFMA GEMM -> GELU -> s[N] ----------------
// Block: 64 rows, 512 threads (8 waves). ~66KB LDS -> 2 blocks/CU = 16 waves/CU.
// ILP: all 16 LN loads hoisted; B-frags prefetched one K-step ahead.
__global__ __launch_bounds__(512, 4) void score_kernel(
    const float* __restrict__ feats, const float* __restrict__ ln_w,
    const float* __restrict__ ln_b, const unsigned short* __restrict__ w1p,
    const float* __restrict__ b1, const float* __restrict__ w2,
    const float* __restrict__ b2, float* __restrict__ s_out) {
  __shared__ __align__(16) unsigned short xs[RB * 512];  // 64KB bf16 x-tile, XOR-swizzled
  __shared__ float sred[8][RB];
  char* xsb = (char*)xs;
  const int tid = threadIdx.x;
  const int lane = tid & 63;
  const int wid = tid >> 6;
  const long row0 = (long)blockIdx.x * RB;

  // ---- Phase 1: LayerNorm, 8 rows per wave; ALL loads issued before any compute ----
  const int c0 = lane * 4;
  const float4 lw0 = *(const float4*)(ln_w + c0);
  const float4 lw1 = *(const float4*)(ln_w + 256 + c0);
  const float4 lb0 = *(const float4*)(ln_b + c0);
  const float4 lb1 = *(const float4*)(ln_b + 256 + c0);

  float4 va[8], vb[8];
  {
    const float* bp = feats + (row0 + wid * 8) * 512 + c0;
    #pragma unroll
    for (int rr = 0; rr < 8; ++rr) {
      va[rr] = *(const float4*)(bp + rr * 512);
      vb[rr] = *(const float4*)(bp + rr * 512 + 256);
    }
  }
  #pragma unroll
  for (int rr = 0; rr < 8; ++rr) {
    const int row = wid * 8 + rr;
    const float4 v0 = va[rr];
    const float4 v1 = vb[rr];
    float sum = (v0.x + v0.y) + (v0.z + v0.w) + (v1.x + v1.y) + (v1.z + v1.w);
    float sq  = v0.x * v0.x + v0.y * v0.y + v0.z * v0.z + v0.w * v0.w
              + v1.x * v1.x + v1.y * v1.y + v1.z * v1.z + v1.w * v1.w;
    #pragma unroll
    for (int off = 32; off >= 1; off >>= 1) {
      sum += __shfl_xor(sum, off);
      sq  += __shfl_xor(sq, off);
    }
    const float mean = sum * (1.0f / 512.0f);
    const float var  = sq * (1.0f / 512.0f) - mean * mean;
    const float rstd = rsqrtf(var + 1e-5f);
    const float x0 = (v0.x - mean) * rstd * lw0.x + lb0.x;
    const float x1 = (v0.y - mean) * rstd * lw0.y + lb0.y;
    const float x2 = (v0.z - mean) * rstd * lw0.z + lb0.z;
    const float x3 = (v0.w - mean) * rstd * lw0.w + lb0.w;
    const float y0 = (v1.x - mean) * rstd * lw1.x + lb1.x;
    const float y1 = (v1.y - mean) * rstd * lw1.y + lb1.y;
    const float y2 = (v1.z - mean) * rstd * lw1.z + lb1.z;
    const float y3 = (v1.w - mean) * rstd * lw1.w + lb1.w;
    const unsigned int p0 = f2bf(x0) | (f2bf(x1) << 16);
    const unsigned int p1 = f2bf(x2) | (f2bf(x3) << 16);
    const unsigned int p2 = f2bf(y0) | (f2bf(y1) << 16);
    const unsigned int p3 = f2bf(y2) | (f2bf(y3) << 16);
    const unsigned int a0 = ((unsigned int)(row * 1024 + c0 * 2)) ^ (((unsigned int)(row & 7)) << 4);
    const unsigned int a1 = ((unsigned int)(row * 1024 + 512 + c0 * 2)) ^ (((unsigned int)(row & 7)) << 4);
    *(uint2*)(xsb + a0) = make_uint2(p0, p1);
    *(uint2*)(xsb + a1) = make_uint2(p2, p3);
  }
  __syncthreads();

  // ---- Phase 2: GEMM  h[64x256] = x[64x512] @ w1; wave owns 32 N-cols ----
  const int l15 = lane & 15, l4 = lane >> 4;
  const int nb = wid * 32;
  f32x4 acc[4][2];
  #pragma unroll
  for (int i = 0; i < 4; ++i)
    #pragma unroll
    for (int j = 0; j < 2; ++j)
      acc[i][j] = f32x4{0.f, 0.f, 0.f, 0.f};

  bf16x8 bvc[2];
  #pragma unroll
  for (int nt = 0; nt < 2; ++nt)
    bvc[nt] = *(const bf16x8*)(w1p + (((l4 << 8) + nb + nt * 16 + l15) << 3));

  #pragma unroll
  for (int ks = 0; ks < 16; ++ks) {
    bf16x8 av[4], bvn[2];
    if (ks < 15) {  // prefetch next K-step's B-frags (L2 latency hides under MFMA)
      #pragma unroll
      for (int nt = 0; nt < 2; ++nt)
        bvn[nt] = *(const bf16x8*)(w1p + (((((ks + 1) * 4 + l4) << 8) + nb + nt * 16 + l15) << 3));
    }
    #pragma unroll
    for (int mt = 0; mt < 4; ++mt) {
      const int row = mt * 16 + l15;
      const unsigned int ad =
          ((unsigned int)(row * 1024 + ks * 64 + l4 * 16)) ^ (((unsigned int)(row & 7)) << 4);
      av[mt] = *(const bf16x8*)(xsb + ad);
    }
    #pragma unroll
    for (int mt = 0; mt < 4; ++mt)
      #pragma unroll
      for (int nt = 0; nt < 2; ++nt)
        acc[mt][nt] = __builtin_amdgcn_mfma_f32_16x16x32_bf16(av[mt], bvc[nt], acc[mt][nt], 0, 0, 0);
    bvc[0] = bvn[0];
    bvc[1] = bvn[1];
  }

  // ---- Epilogue: s_row = sum_n gelu(acc + b1) * w2 ----
  float b1v[2], w2v[2];
  #pragma unroll
  for (int nt = 0; nt < 2; ++nt) {
    const int n = nb + nt * 16 + l15;
    b1v[nt] = b1[n];
    w2v[nt] = w2[n];
  }
  #pragma unroll
  for (int mt = 0; mt < 4; ++mt) {
    #pragma unroll
    for (int r = 0; r < 4; ++r) {
      float v = 0.0f;
      #pragma unroll
      for (int nt = 0; nt < 2; ++nt) {
        const float h = acc[mt][nt][r] + b1v[nt];
        v += gelu_f(h) * w2v[nt];
      }
      v += __shfl_xor(v, 1);
      v += __shfl_xor(v, 2);
      v += __shfl_xor(v, 4);
      v += __shfl_xor(v, 8);
      if (l15 == 0) sred[wid][mt * 16 + l4 * 4 + r] = v;
    }
  }
  __syncthreads();
  if (wid == 0) {
    float sv = b2[0];
    #pragma unroll
    for (int w = 0; w < 8; ++w) sv += sred[w][lane];
    s_out[row0 + lane] = sv;
  }
}

// ---------------- seg_stats: per-segment max and 1/sum(exp) (s is L2-resident, 2MB) ----
__global__ __launch_bounds__(512) void seg_stats(const float* __restrict__ s,
                                                 const int* __restrict__ offs,
                                                 float* __restrict__ mz) {
  const int b = blockIdx.x;
  const int start = offs[b], end = offs[b + 1];
  const int tid = threadIdx.x;
  const int lane = tid & 63, wid = tid >> 6;
  __shared__ float red[8];

  float lm = -INFINITY;
  for (int i = start + tid; i < end; i += 512) lm = fmaxf(lm, s[i]);
  #pragma unroll
  for (int off = 32; off >= 1; off >>= 1) lm = fmaxf(lm, __shfl_xor(lm, off));
  if (lane == 0) red[wid] = lm;
  __syncthreads();
  float m = red[0];
  #pragma unroll
  for (int w = 1; w < 8; ++w) m = fmaxf(m, red[w]);
  __syncthreads();

  float ls = 0.0f;
  for (int i = start + tid; i < end; i += 512) ls += __expf(s[i] - m);
  #pragma unroll
  for (int off = 32; off >= 1; off >>= 1) ls += __shfl_xor(ls, off);
  if (lane == 0) red[wid] = ls;
  __syncthreads();
  if (tid == 0) {
    float z = 0.0f;
    #pragma unroll
    for (int w = 0; w < 8; ++w) z += red[w];
    mz[b] = m;
    mz[NSEG + b] = 1.0f / z;
  }
}

// ---------------- pool: streaming partial pool, final weights, no atomics ----------------
// Block = 256 rows x 512 threads (thread owns one f32 column). 4 independent FMA chains.
__global__ __launch_bounds__(512) void pool_kernel(
    const float* __restrict__ feats, const float* __restrict__ s,
    const float* __restrict__ mz, const int* __restrict__ offs,
    float* __restrict__ Pp) {
  __shared__ float sw[CB];
  __shared__ int sh_bound[66];
  __shared__ int sh_meta[3];  // npart, pbase, seg0
  const int tid = threadIdx.x;
  const int lane = tid & 63, wid = tid >> 6;
  const int r0 = blockIdx.x * CB;

  if (wid == 0) {
    const int c = offs[lane + 1];  // lanes 0..63 -> offs[1..64]
    const bool before = (c <= r0);
    const unsigned long long mb = __ballot(before && (c & (CB - 1)));
    const unsigned long long ms = __ballot(before);
    const unsigned long long mi = __ballot((c > r0) && (c < r0 + CB));
    if ((c > r0) && (c < r0 + CB)) {
      const int rank = __popcll(mi & ((1ull << lane) - 1ull));
      sh_bound[rank + 1] = c - r0;
    }
    if (lane == 0) {
      const int npart = __popcll(mi) + 1;
      sh_bound[0] = 0;
      sh_bound[npart] = CB;
      sh_meta[0] = npart;
      sh_meta[1] = blockIdx.x + __popcll(mb);
      sh_meta[2] = __popcll(ms);
    }
  }
  __syncthreads();
  const int npart = sh_meta[0], pbase = sh_meta[1], seg0 = sh_meta[2];

  // final per-row weights into LDS (threads 0..255)
  if (tid < CB) {
    int k = 0;
    for (int i = 1; i < npart; ++i) k += (sh_bound[i] <= tid) ? 1 : 0;
    sw[tid] = __expf(s[r0 + tid] - mz[seg0 + k]) * mz[NSEG + seg0 + k];
  }
  __syncthreads();

  const float* fp = feats + (size_t)r0 * 512;
  float a0 = 0.f, a1 = 0.f, a2 = 0.f, a3 = 0.f;
  int k = 0;
  #pragma unroll 4
  for (int r = 0; r < CB; ++r) {
    if (r == sh_bound[k + 1]) {          // wave-uniform, rare
      Pp[(size_t)(pbase + k) * 512 + tid] = (a0 + a1) + (a2 + a3);
      a0 = a1 = a2 = a3 = 0.f;
      ++k;
    }
    const float v = sw[r] * fp[(size_t)r * 512 + tid];
    if ((r & 3) == 0) a0 += v;
    else if ((r & 3) == 1) a1 += v;
    else if ((r & 3) == 2) a2 += v;
    else a3 += v;
  }
  Pp[(size_t)(pbase + k) * 512 + tid] = (a0 + a1) + (a2 + a3);
}

// ---------------- combine: out[b][c] = sum over b's parts of Pp[p][c] ----------------
__global__ __launch_bounds__(512) void combine_kernel(
    const int* __restrict__ offs, const float* __restrict__ Pp,
    float* __restrict__ out) {
  const int b = blockIdx.x;
  const int tid = threadIdx.x;
  const int lane = tid & 63, wid = tid >> 6;
  __shared__ int s_lohi[2];

  if (wid == 0) {
    const int c = offs[lane + 1];
    const unsigned long long nal = __ballot((c & (CB - 1)) != 0);
    if (lane == 0) {
      const unsigned long long mlo = (b == 0) ? 0ull : ((1ull << b) - 1ull);
      const unsigned long long mhi = (b == 63) ? ~0ull : ((1ull << (b + 1)) - 1ull);
      s_lohi[0] = (offs[b] >> 8) + __popcll(nal & mlo);
      s_lohi[1] = (offs[b + 1] >> 8) + __popcll(nal & mhi) - 1;
    }
  }
  __syncthreads();
  const int lo = s_lohi[0], hi = s_lohi[1];

  float a0 = 0.f, a1 = 0.f, a2 = 0.f, a3 = 0.f;
  int p = lo;
  for (; p + 3 <= hi; p += 4) {
    a0 += Pp[(size_t)p * 512 + tid];
    a1 += Pp[(size_t)(p + 1) * 512 + tid];
    a2 += Pp[(size_t)(p + 2) * 512 + tid];
    a3 += Pp[(size_t)(p + 3) * 512 + tid];
  }
  for (; p <= hi; ++p) a0 += Pp[(size_t)p * 512 + tid];
  out[b * 512 + tid] = (a0 + a1) + (a2 + a3);
}

extern "C" void kernel_launch(void* const* d_in, const int* in_sizes, int n_in,
                              void* d_out, int out_size, void* d_ws, size_t ws_size,
                              hipStream_t stream) {
  const float* feats = (const float*)d_in[0];
  const float* ln_w  = (const float*)d_in[1];
  const float* ln_b  = (const float*)d_in[2];
  const float* w1    = (const float*)d_in[3];
  const float* b1    = (const float*)d_in[4];
  const float* w2    = (const float*)d_in[5];
  const float* b2    = (const float*)d_in[6];
  const int* offs    = (const int*)d_in[7];
  float* out = (float*)d_out;

  char* ws = (char*)d_ws;
  unsigned short* w1p = (unsigned short*)(ws);                    // 256 KB
  float* s_buf = (float*)(ws + 262144);                           // 2 MB
  float* mz    = (float*)(ws + 262144 + 2097152);                 // 128 f32
  float* Pp    = (float*)(ws + 262144 + 2097152 + 4096);          // MAXP2*512 f32 (~4.3 MB)

  prep_w1<<<64, 256, 0, stream>>>(w1, w1p);
  score_kernel<<<NPTS / RB, 512, 0, stream>>>(feats, ln_w, ln_b, w1p, b1, w2, b2, s_buf);
  seg_stats<<<NSEG, 512, 0, stream>>>(s_buf, offs, mz);
  pool_kernel<<<NPB, 512, 0, stream>>>(feats, s_buf, mz, offs, Pp);
  combine_kernel<<<NSEG, 512, 0, stream>>>(offs, Pp, out);
}